// Round 7
// baseline (189.859 us; speedup 1.0000x reference)
//
#include <hip/hip_runtime.h>

// loss = sum_i ( -2*logits[i, t_i] + top1_i + top2_i )
// (log_softmax's lse cancels exactly: -2(x_t - lse) + (m1 - lse) + (m2 - lse)
//  = m1 + m2 - 2 x_t, since CONTRASTIVE_NUM == 2 == broadcast count)
// Harness delivers integer inputs as int32.
//
// R7: R5 + 4 rows per block with INDEPENDENT register accumulators per row —
// no barrier between rows (R6's mistake), one reduction + one barrier at block
// end. Grid 2048x1024 -> 4 block generations (vs R5's 16), same 512-concurrent
// -stream pattern.

#define NROWS 8192
#define VOCAB 32000
#define TPB 1024
#define NWAVES (TPB / 64)
#define RPB 4                      // rows per block
#define NBLOCKS (NROWS / RPB)      // 2048

__global__ __launch_bounds__(TPB) void cce_row_kernel(const float* __restrict__ logits,
                                                      const int* __restrict__ target,
                                                      float* __restrict__ row_partial) {
    const int row0 = blockIdx.x * RPB;
    const int wave = threadIdx.x >> 6;
    const int lane = threadIdx.x & 63;

    // Early target gathers: thread r owns row row0+r's target value.
    float tv = 0.0f;
    if (threadIdx.x < RPB) {
        const int t = target[row0 + threadIdx.x];
        tv = logits[(size_t)(row0 + threadIdx.x) * VOCAB + (size_t)t];
    }

    float m1[RPB], m2[RPB];
    #pragma unroll
    for (int r = 0; r < RPB; ++r) { m1[r] = -INFINITY; m2[r] = -INFINITY; }

    // Stream the 4 rows back-to-back; no syncs between rows.
    #pragma unroll
    for (int r = 0; r < RPB; ++r) {
        const float4* rp = reinterpret_cast<const float4*>(logits + (size_t)(row0 + r) * VOCAB);
        float a1 = m1[r], a2 = m2[r];
        for (int i = threadIdx.x; i < VOCAB / 4; i += TPB) {
            float4 v = rp[i];
            a2 = fmaxf(a2, fminf(a1, v.x)); a1 = fmaxf(a1, v.x);
            a2 = fmaxf(a2, fminf(a1, v.y)); a1 = fmaxf(a1, v.y);
            a2 = fmaxf(a2, fminf(a1, v.z)); a1 = fmaxf(a1, v.z);
            a2 = fmaxf(a2, fminf(a1, v.w)); a1 = fmaxf(a1, v.w);
        }
        m1[r] = a1; m2[r] = a2;
    }

    // Wave butterfly reductions for all rows (end of block, once).
    #pragma unroll
    for (int r = 0; r < RPB; ++r) {
        float a1 = m1[r], a2 = m2[r];
        #pragma unroll
        for (int off = 32; off > 0; off >>= 1) {
            float o1 = __shfl_xor(a1, off, 64);
            float o2 = __shfl_xor(a2, off, 64);
            float n1 = fmaxf(a1, o1);
            float n2 = fmaxf(fminf(a1, o1), fmaxf(a2, o2));
            a1 = n1; a2 = n2;
        }
        m1[r] = a1; m2[r] = a2;
    }

    __shared__ float s1[RPB][NWAVES], s2[RPB][NWAVES];
    if (lane == 0) {
        #pragma unroll
        for (int r = 0; r < RPB; ++r) { s1[r][wave] = m1[r]; s2[r][wave] = m2[r]; }
    }
    __syncthreads();

    if (threadIdx.x < RPB) {
        const int r = threadIdx.x;
        float a1 = s1[r][0], a2 = s2[r][0];
        #pragma unroll
        for (int w = 1; w < NWAVES; ++w) {
            float o1 = s1[r][w], o2 = s2[r][w];
            float n1 = fmaxf(a1, o1);
            float n2 = fmaxf(fminf(a1, o1), fmaxf(a2, o2));
            a1 = n1; a2 = n2;
        }
        row_partial[row0 + r] = a1 + a2 - 2.0f * tv;
    }
}

__global__ __launch_bounds__(256) void cce_reduce_kernel(const float* __restrict__ row_partial,
                                                         float* __restrict__ out) {
    float s = 0.0f;
    for (int i = threadIdx.x; i < NROWS; i += 256) s += row_partial[i];
    #pragma unroll
    for (int off = 32; off > 0; off >>= 1) s += __shfl_xor(s, off, 64);

    __shared__ float ws[4];
    const int wave = threadIdx.x >> 6;
    const int lane = threadIdx.x & 63;
    if (lane == 0) ws[wave] = s;
    __syncthreads();
    if (threadIdx.x == 0) out[0] = ws[0] + ws[1] + ws[2] + ws[3];
}

extern "C" void kernel_launch(void* const* d_in, const int* in_sizes, int n_in,
                              void* d_out, int out_size, void* d_ws, size_t ws_size,
                              hipStream_t stream) {
    const float* logits = (const float*)d_in[0];
    const int* target = (const int*)d_in[1];
    float* out = (float*)d_out;
    float* row_partial = (float*)d_ws;  // NROWS floats = 32 KiB

    cce_row_kernel<<<NBLOCKS, TPB, 0, stream>>>(logits, target, row_partial);
    cce_reduce_kernel<<<1, 256, 0, stream>>>(row_partial, out);
}

// Round 8
// 159.549 us; speedup vs baseline: 1.1900x; 1.1900x over previous
//
#include <hip/hip_runtime.h>

// loss = sum_i ( -2*logits[i, t_i] + top1_i + top2_i )
// (log_softmax's lse cancels exactly: -2(x_t - lse) + (m1 - lse) + (m2 - lse)
//  = m1 + m2 - 2 x_t, since CONTRASTIVE_NUM == 2 == broadcast count)
// Harness delivers integer inputs as int32.
//
// R8: exact R5 structure (8192 blocks x 1024 thr, one row per block — best so
// far at 181.7 us), single variable changed: nontemporal loads on the stream
// (no L2 allocate for a zero-reuse 1 GB stream).

#define NROWS 8192
#define VOCAB 32000
#define TPB 1024
#define NWAVES (TPB / 64)

typedef float floatx4 __attribute__((ext_vector_type(4)));

__global__ __launch_bounds__(TPB) void cce_row_kernel(const float* __restrict__ logits,
                                                      const int* __restrict__ target,
                                                      float* __restrict__ row_partial) {
    const int row = blockIdx.x;
    const floatx4* rp = reinterpret_cast<const floatx4*>(logits + (size_t)row * VOCAB);

    // Issue the target gather early (thread 0); latency hides under the stream.
    float tv = 0.0f;
    if (threadIdx.x == 0) {
        const int t = target[row];
        tv = logits[(size_t)row * VOCAB + (size_t)t];
    }

    // 8000 float4 per row / 1024 threads: 7-8 iterations per thread.
    float m1 = -INFINITY, m2 = -INFINITY;
    for (int i = threadIdx.x; i < VOCAB / 4; i += TPB) {
        floatx4 v = __builtin_nontemporal_load(&rp[i]);
        m2 = fmaxf(m2, fminf(m1, v.x)); m1 = fmaxf(m1, v.x);
        m2 = fmaxf(m2, fminf(m1, v.y)); m1 = fmaxf(m1, v.y);
        m2 = fmaxf(m2, fminf(m1, v.z)); m1 = fmaxf(m1, v.z);
        m2 = fmaxf(m2, fminf(m1, v.w)); m1 = fmaxf(m1, v.w);
    }

    // 64-lane butterfly reduction of the (m1, m2) pair
    #pragma unroll
    for (int off = 32; off > 0; off >>= 1) {
        float o1 = __shfl_xor(m1, off, 64);
        float o2 = __shfl_xor(m2, off, 64);
        float nm1 = fmaxf(m1, o1);
        float nm2 = fmaxf(fminf(m1, o1), fmaxf(m2, o2));
        m1 = nm1; m2 = nm2;
    }

    __shared__ float s1[NWAVES], s2[NWAVES];
    const int wave = threadIdx.x >> 6;
    const int lane = threadIdx.x & 63;
    if (lane == 0) { s1[wave] = m1; s2[wave] = m2; }
    __syncthreads();

    if (threadIdx.x == 0) {
        m1 = s1[0]; m2 = s2[0];
        #pragma unroll
        for (int w = 1; w < NWAVES; ++w) {
            float o1 = s1[w], o2 = s2[w];
            float nm1 = fmaxf(m1, o1);
            float nm2 = fmaxf(fminf(m1, o1), fmaxf(m2, o2));
            m1 = nm1; m2 = nm2;
        }
        row_partial[row] = m1 + m2 - 2.0f * tv;
    }
}

__global__ __launch_bounds__(256) void cce_reduce_kernel(const float* __restrict__ row_partial,
                                                         float* __restrict__ out) {
    float s = 0.0f;
    for (int i = threadIdx.x; i < NROWS; i += 256) s += row_partial[i];
    #pragma unroll
    for (int off = 32; off > 0; off >>= 1) s += __shfl_xor(s, off, 64);

    __shared__ float ws[4];
    const int wave = threadIdx.x >> 6;
    const int lane = threadIdx.x & 63;
    if (lane == 0) ws[wave] = s;
    __syncthreads();
    if (threadIdx.x == 0) out[0] = ws[0] + ws[1] + ws[2] + ws[3];
}

extern "C" void kernel_launch(void* const* d_in, const int* in_sizes, int n_in,
                              void* d_out, int out_size, void* d_ws, size_t ws_size,
                              hipStream_t stream) {
    const float* logits = (const float*)d_in[0];
    const int* target = (const int*)d_in[1];
    float* out = (float*)d_out;
    float* row_partial = (float*)d_ws;  // NROWS floats = 32 KiB

    cce_row_kernel<<<NROWS, TPB, 0, stream>>>(logits, target, row_partial);
    cce_reduce_kernel<<<1, 256, 0, stream>>>(row_partial, out);
}